// Round 1
// baseline (6050.257 us; speedup 1.0000x reference)
//
#include <hip/hip_runtime.h>
#include <stdint.h>
#include <stddef.h>

// ---------------------------------------------------------------------------
// Discriminator: embedding [64,512] -> GRU(512->1024, 512 steps) -> FC(1024->2)
// Plan:
//   k1 embed_k : gather emb rows -> X fp16 [S*B, 512]   (row = s*64+b)
//   k2 wconv   : w_ih fp32 -> fp16
//   k3 gemm_gx : GX = X @ w_ih^T + b_ih  -> fp16 [S*B, 3072]  (MFMA 128x128 tile)
//   k4 gru_rec : persistent 256-WG kernel, 4 batch-groups x 64 unit-groups,
//                w_hh slice LDS-resident fp16, per-step atomic barrier per group
//   k5 fc_k    : logits = h_last @ fc_w^T + fc_b -> d_out fp32 [64,2]
// ---------------------------------------------------------------------------

typedef _Float16 f16;
typedef _Float16 f16x4 __attribute__((ext_vector_type(4)));
typedef _Float16 f16x8 __attribute__((ext_vector_type(8)));
typedef float f32x4 __attribute__((ext_vector_type(4)));

#define NB 64      // batch
#define NS 512     // seq len
#define NE 512     // embedding dim
#define NH 1024    // hidden
#define G3 3072    // 3*NH

// ---------------------------------------------------------------- embedding
__global__ __launch_bounds__(256) void embed_k(const int* __restrict__ seq,
                                               const float* __restrict__ emb,
                                               f16* __restrict__ X) {
  int rr = blockIdx.x * 4 + (threadIdx.x >> 6);   // row = s*64 + b
  int lane = threadIdx.x & 63;
  int s = rr >> 6, b = rr & 63;
  int idx = seq[b * NS + s];
  const float* src = emb + (size_t)idx * NE + lane * 8;
  float4 v0 = *(const float4*)(src);
  float4 v1 = *(const float4*)(src + 4);
  f16x8 o;
  o[0] = (f16)v0.x; o[1] = (f16)v0.y; o[2] = (f16)v0.z; o[3] = (f16)v0.w;
  o[4] = (f16)v1.x; o[5] = (f16)v1.y; o[6] = (f16)v1.z; o[7] = (f16)v1.w;
  *(f16x8*)(&X[(size_t)rr * NE + lane * 8]) = o;
}

// ---------------------------------------------------------------- w_ih -> fp16
__global__ __launch_bounds__(256) void wconv(const float* __restrict__ w,
                                             f16* __restrict__ o) {
  int i = (blockIdx.x * 256 + threadIdx.x) * 4;
  float4 v = *(const float4*)(&w[i]);
  f16x4 t = {(f16)v.x, (f16)v.y, (f16)v.z, (f16)v.w};
  *(f16x4*)(&o[i]) = t;
}

// ---------------------------------------------------------------- gx GEMM
// C[m,g] = sum_k X[m,k] * W[g,k] + bih[g];  M=32768 N=3072 K=512
__global__ __launch_bounds__(256) void gemm_gx(const f16* __restrict__ X,
                                               const f16* __restrict__ W,
                                               const float* __restrict__ bih,
                                               f16* __restrict__ GX) {
  __shared__ f16 As[128][40];   // +8 pad: frag-read 2-way banks only
  __shared__ f16 Bs[128][40];
  int tm = blockIdx.x & 255, tn = blockIdx.x >> 8;   // 256 x 24
  int m0 = tm * 128, n0 = tn * 128;
  int tid = threadIdx.x, lane = tid & 63, w = tid >> 6;
  int wm = w & 1, wn = w >> 1;
  f32x4 acc[4][4] = {};
  for (int k0 = 0; k0 < 512; k0 += 32) {
    __syncthreads();
    #pragma unroll
    for (int i = 0; i < 2; i++) {
      int c = tid + i * 256;          // 512 chunks of 16B per operand
      int r = c >> 2, seg = c & 3;
      *(f16x8*)(&As[r][seg * 8]) = *(const f16x8*)(&X[(size_t)(m0 + r) * 512 + k0 + seg * 8]);
      *(f16x8*)(&Bs[r][seg * 8]) = *(const f16x8*)(&W[(size_t)(n0 + r) * 512 + k0 + seg * 8]);
    }
    __syncthreads();
    f16x8 af[4], bf[4];
    int rA = lane & 15, kA = (lane >> 4) * 8;
    #pragma unroll
    for (int i = 0; i < 4; i++) af[i] = *(const f16x8*)(&As[wm * 64 + i * 16 + rA][kA]);
    #pragma unroll
    for (int j = 0; j < 4; j++) bf[j] = *(const f16x8*)(&Bs[wn * 64 + j * 16 + rA][kA]);
    #pragma unroll
    for (int i = 0; i < 4; i++)
      #pragma unroll
      for (int j = 0; j < 4; j++)
        acc[i][j] = __builtin_amdgcn_mfma_f32_16x16x32_f16(af[i], bf[j], acc[i][j], 0, 0, 0);
  }
  int col = lane & 15, rq = lane >> 4;
  #pragma unroll
  for (int j = 0; j < 4; j++) {
    int g = n0 + wn * 64 + j * 16 + col;
    float bias = bih[g];
    #pragma unroll
    for (int i = 0; i < 4; i++) {
      int mbase = m0 + wm * 64 + i * 16 + rq * 4;
      #pragma unroll
      for (int q = 0; q < 4; q++)
        GX[(size_t)(mbase + q) * G3 + g] = (f16)(acc[i][j][q] + bias);
    }
  }
}

// ---------------------------------------------------------------- GRU recurrence
// 256 WGs: bg = blk>>6 (4 batch-groups of 16), ug = blk&63 (64 unit-groups of 16).
// w_hh slice [48 rows x 1024] fp16 in LDS. One atomic barrier per step per group.
__global__ __launch_bounds__(256, 1) void gru_rec(const float* __restrict__ whh,
                                                  const float* __restrict__ bhh,
                                                  const f16* __restrict__ GX,
                                                  f16* __restrict__ hb,       // [2][64][1024]
                                                  float* __restrict__ hlast,  // [64][1024]
                                                  uint32_t* __restrict__ cnt) {
  __shared__ f16 wl[48][1032];          // pad 8 -> 2-way bank alias only
  __shared__ float red[4][3][16][17];   // pad 17 -> conflict-free reduce
  const int tid = threadIdx.x, lane = tid & 63, wv = tid >> 6;
  const int bg = blockIdx.x >> 6, ug = blockIdx.x & 63;
  const int brow0 = bg * 16;

  // stage w_hh slice -> LDS fp16. row lr = gate*16+c -> whh[gate*1024 + ug*16 + c]
  for (int lr = 0; lr < 48; lr++) {
    const float* srow = whh + (size_t)((lr >> 4) * NH + ug * 16 + (lr & 15)) * NH;
    float4 v = *(const float4*)(srow + tid * 4);
    f16x4 t = {(f16)v.x, (f16)v.y, (f16)v.z, (f16)v.w};
    *(f16x4*)(&wl[lr][tid * 4]) = t;
  }
  const int b = tid >> 4, u = tid & 15;
  const int ugl = ug * 16 + u;
  const float bh_r = bhh[ugl], bh_z = bhh[NH + ugl], bh_n = bhh[2 * NH + ugl];
  float hown = 0.f;
  uint32_t* myc = cnt + bg * 32;        // 128B-separated counters
  __syncthreads();

  #pragma unroll 1
  for (int s = 0; s < NS; s++) {
    // prefetch gx_t (independent of h) before the barrier
    const f16* gxp = GX + ((size_t)s * NB + brow0 + b) * G3 + ugl;
    f16 gr16 = gxp[0], gz16 = gxp[NH], gn16 = gxp[2 * NH];

    if (s > 0) {
      if (tid == 0) {
        const uint32_t target = 64u * (uint32_t)s;
        while (__hip_atomic_load(myc, __ATOMIC_RELAXED, __HIP_MEMORY_SCOPE_AGENT) < target)
          __builtin_amdgcn_s_sleep(1);
        (void)__hip_atomic_load(myc, __ATOMIC_ACQUIRE, __HIP_MEMORY_SCOPE_AGENT); // inv L1/L2
      }
      __syncthreads();
    }

    const f16* hsrc = hb + (size_t)(s & 1) * NB * NH;
    // A-frags: wave wv covers k in [wv*256, wv*256+256)
    f16x8 af[8];
    {
      const f16* hrow = hsrc + (size_t)(brow0 + (lane & 15)) * NH + wv * 256 + (lane >> 4) * 8;
      #pragma unroll
      for (int kk = 0; kk < 8; kk++) af[kk] = *(const f16x8*)(hrow + kk * 32);
    }
    f32x4 acc[3] = {};
    #pragma unroll
    for (int kk = 0; kk < 8; kk++) {
      const int kof = wv * 256 + kk * 32 + (lane >> 4) * 8;
      #pragma unroll
      for (int n = 0; n < 3; n++) {
        f16x8 bfrag = *(const f16x8*)(&wl[n * 16 + (lane & 15)][kof]);
        acc[n] = __builtin_amdgcn_mfma_f32_16x16x32_f16(af[kk], bfrag, acc[n], 0, 0, 0);
      }
    }
    {
      const int col = lane & 15, rq = lane >> 4;
      #pragma unroll
      for (int n = 0; n < 3; n++)
        #pragma unroll
        for (int q = 0; q < 4; q++)
          red[wv][n][rq * 4 + q][col] = acc[n][q];
    }
    __syncthreads();
    float ghr = bh_r, ghz = bh_z, ghn = bh_n;
    #pragma unroll
    for (int w2 = 0; w2 < 4; w2++) {
      ghr += red[w2][0][b][u];
      ghz += red[w2][1][b][u];
      ghn += red[w2][2][b][u];
    }
    const float xr = (float)gr16, xz = (float)gz16, xn = (float)gn16;
    const float r = 1.f / (1.f + __expf(-(xr + ghr)));
    const float z = 1.f / (1.f + __expf(-(xz + ghz)));
    float nv;
    {
      const float a = xn + r * ghn;
      const float t = __expf(-2.f * fabsf(a));
      nv = (1.f - t) / (1.f + t);
      nv = a < 0.f ? -nv : nv;
    }
    hown = (1.f - z) * nv + z * hown;
    f16* hdst = hb + (size_t)((s + 1) & 1) * NB * NH;
    hdst[(size_t)(brow0 + b) * NH + ugl] = (f16)hown;
    if (s == NS - 1) hlast[(size_t)(brow0 + b) * NH + ugl] = hown;
    __syncthreads();   // all stores retired (vmcnt(0) pre-barrier) + red WAR safety
    if (tid == 0)
      __hip_atomic_fetch_add(myc, 1u, __ATOMIC_RELEASE, __HIP_MEMORY_SCOPE_AGENT); // wb L2
  }
}

// ---------------------------------------------------------------- FC head
__global__ __launch_bounds__(64) void fc_k(const float* __restrict__ hl,
                                           const float* __restrict__ fw,
                                           const float* __restrict__ fb,
                                           float* __restrict__ out) {
  int b = blockIdx.x, t = threadIdx.x;
  float a0 = 0.f, a1 = 0.f;
  for (int k = t; k < NH; k += 64) {
    float h = hl[b * NH + k];
    a0 += h * fw[k];
    a1 += h * fw[NH + k];
  }
  #pragma unroll
  for (int off = 32; off; off >>= 1) {
    a0 += __shfl_down(a0, off);
    a1 += __shfl_down(a1, off);
  }
  if (t == 0) {
    out[b * 2 + 0] = a0 + fb[0];
    out[b * 2 + 1] = a1 + fb[1];
  }
}

// ---------------------------------------------------------------- launcher
extern "C" void kernel_launch(void* const* d_in, const int* in_sizes, int n_in,
                              void* d_out, int out_size, void* d_ws, size_t ws_size,
                              hipStream_t stream) {
  const int*   seq = (const int*)d_in[0];
  const float* emb = (const float*)d_in[1];
  const float* wih = (const float*)d_in[2];
  const float* whh = (const float*)d_in[3];
  const float* bih = (const float*)d_in[4];
  const float* bhh = (const float*)d_in[5];
  const float* fcw = (const float*)d_in[6];
  const float* fcb = (const float*)d_in[7];
  float* out = (float*)d_out;

  char* ws = (char*)d_ws;
  size_t off = 0;
  f16* X = (f16*)(ws + off);   off += (size_t)NS * NB * NE * 2;   // 33.6 MB
  f16* W16 = (f16*)(ws + off); off += (size_t)G3 * NE * 2;        // 3.1 MB
  f16* GX = (f16*)(ws + off);  off += (size_t)NS * NB * G3 * 2;   // 201 MB
  f16* HB = (f16*)(ws + off);  off += (size_t)2 * NB * NH * 2;    // 256 KB
  float* HL = (float*)(ws + off); off += (size_t)NB * NH * 4;     // 256 KB
  uint32_t* CNT = (uint32_t*)(ws + off); off += 4 * 128;
  if (ws_size < off) return;  // insufficient workspace -> fail visibly, no OOB

  hipMemsetAsync(HB, 0, (size_t)NB * NH * 2, stream);  // h0 = 0 (parity-0 buffer)
  hipMemsetAsync(CNT, 0, 4 * 128, stream);             // barrier counters

  embed_k<<<(NS * NB) / 4, 256, 0, stream>>>(seq, emb, X);
  wconv<<<(G3 * NE) / 1024, 256, 0, stream>>>(wih, W16);
  gemm_gx<<<256 * 24, 256, 0, stream>>>(X, W16, bih, GX);
  gru_rec<<<256, 256, 0, stream>>>(whh, bhh, GX, HB, HL, CNT);
  fc_k<<<NB, 64, 0, stream>>>(HL, fcw, fcb, out);
}

// Round 2
// 2181.411 us; speedup vs baseline: 2.7736x; 2.7736x over previous
//
#include <hip/hip_runtime.h>
#include <stdint.h>
#include <stddef.h>

// ---------------------------------------------------------------------------
// Discriminator: embedding [64,512] -> GRU(512->1024, 512 steps) -> FC(1024->2)
//   k1 embed_k : gather emb rows -> X fp16 [S*B, 512]   (row = s*64+b)
//   k2 wconv   : w_ih fp32 -> fp16
//   k3 gemm_gx : GX = X @ w_ih^T + b_ih  -> fp16 [S*B, 3072]  (MFMA 128x128 tile)
//   k4 gru_rec : persistent 256-WG kernel, 4 batch-groups x 64 unit-groups,
//                w_hh slice LDS-resident fp16. Cross-WG exchange of h via
//                sc0sc1 (coherence-point) loads/stores + RELAXED atomic
//                counter barrier -- NO buffer_inv / buffer_wbl2 per step.
//   k5 fc_k    : logits = h_last @ fc_w^T + fc_b -> d_out fp32 [64,2]
// ---------------------------------------------------------------------------

typedef _Float16 f16;
typedef _Float16 f16x4 __attribute__((ext_vector_type(4)));
typedef _Float16 f16x8 __attribute__((ext_vector_type(8)));
typedef float f32x4 __attribute__((ext_vector_type(4)));

#define NB 64      // batch
#define NS 512     // seq len
#define NE 512     // embedding dim
#define NH 1024    // hidden
#define G3 3072    // 3*NH

// ---------------------------------------------------------------- embedding
__global__ __launch_bounds__(256) void embed_k(const int* __restrict__ seq,
                                               const float* __restrict__ emb,
                                               f16* __restrict__ X) {
  int rr = blockIdx.x * 4 + (threadIdx.x >> 6);   // row = s*64 + b
  int lane = threadIdx.x & 63;
  int s = rr >> 6, b = rr & 63;
  int idx = seq[b * NS + s];
  const float* src = emb + (size_t)idx * NE + lane * 8;
  float4 v0 = *(const float4*)(src);
  float4 v1 = *(const float4*)(src + 4);
  f16x8 o;
  o[0] = (f16)v0.x; o[1] = (f16)v0.y; o[2] = (f16)v0.z; o[3] = (f16)v0.w;
  o[4] = (f16)v1.x; o[5] = (f16)v1.y; o[6] = (f16)v1.z; o[7] = (f16)v1.w;
  *(f16x8*)(&X[(size_t)rr * NE + lane * 8]) = o;
}

// ---------------------------------------------------------------- w_ih -> fp16
__global__ __launch_bounds__(256) void wconv(const float* __restrict__ w,
                                             f16* __restrict__ o) {
  int i = (blockIdx.x * 256 + threadIdx.x) * 4;
  float4 v = *(const float4*)(&w[i]);
  f16x4 t = {(f16)v.x, (f16)v.y, (f16)v.z, (f16)v.w};
  *(f16x4*)(&o[i]) = t;
}

// ---------------------------------------------------------------- gx GEMM
// C[m,g] = sum_k X[m,k] * W[g,k] + bih[g];  M=32768 N=3072 K=512
__global__ __launch_bounds__(256) void gemm_gx(const f16* __restrict__ X,
                                               const f16* __restrict__ W,
                                               const float* __restrict__ bih,
                                               f16* __restrict__ GX) {
  __shared__ f16 As[128][40];   // +8 pad: frag-read 2-way banks only
  __shared__ f16 Bs[128][40];
  int tm = blockIdx.x & 255, tn = blockIdx.x >> 8;   // 256 x 24
  int m0 = tm * 128, n0 = tn * 128;
  int tid = threadIdx.x, lane = tid & 63, w = tid >> 6;
  int wm = w & 1, wn = w >> 1;
  f32x4 acc[4][4] = {};
  for (int k0 = 0; k0 < 512; k0 += 32) {
    __syncthreads();
    #pragma unroll
    for (int i = 0; i < 2; i++) {
      int c = tid + i * 256;          // 512 chunks of 16B per operand
      int r = c >> 2, seg = c & 3;
      *(f16x8*)(&As[r][seg * 8]) = *(const f16x8*)(&X[(size_t)(m0 + r) * 512 + k0 + seg * 8]);
      *(f16x8*)(&Bs[r][seg * 8]) = *(const f16x8*)(&W[(size_t)(n0 + r) * 512 + k0 + seg * 8]);
    }
    __syncthreads();
    f16x8 af[4], bf[4];
    int rA = lane & 15, kA = (lane >> 4) * 8;
    #pragma unroll
    for (int i = 0; i < 4; i++) af[i] = *(const f16x8*)(&As[wm * 64 + i * 16 + rA][kA]);
    #pragma unroll
    for (int j = 0; j < 4; j++) bf[j] = *(const f16x8*)(&Bs[wn * 64 + j * 16 + rA][kA]);
    #pragma unroll
    for (int i = 0; i < 4; i++)
      #pragma unroll
      for (int j = 0; j < 4; j++)
        acc[i][j] = __builtin_amdgcn_mfma_f32_16x16x32_f16(af[i], bf[j], acc[i][j], 0, 0, 0);
  }
  int col = lane & 15, rq = lane >> 4;
  #pragma unroll
  for (int j = 0; j < 4; j++) {
    int g = n0 + wn * 64 + j * 16 + col;
    float bias = bih[g];
    #pragma unroll
    for (int i = 0; i < 4; i++) {
      int mbase = m0 + wm * 64 + i * 16 + rq * 4;
      #pragma unroll
      for (int q = 0; q < 4; q++)
        GX[(size_t)(mbase + q) * G3 + g] = (f16)(acc[i][j][q] + bias);
    }
  }
}

// ---------------------------------------------------------------- GRU recurrence
// 256 WGs: bg = blk>>6 (4 batch-groups of 16), ug = blk&63 (64 unit-groups of 16).
// w_hh slice [48 rows x 1024] fp16 in LDS. Per-step sync: sc0sc1 data path to
// the coherence point (IF$) + relaxed atomic counter -- no L2 flush/inv.
__global__ __launch_bounds__(256, 1) void gru_rec(const float* __restrict__ whh,
                                                  const float* __restrict__ bhh,
                                                  const f16* __restrict__ GX,
                                                  f16* __restrict__ hb,       // [2][64][1024]
                                                  float* __restrict__ hlast,  // [64][1024]
                                                  uint32_t* __restrict__ cnt) {
  __shared__ f16 wl[48][1032];          // pad 8 -> 2-way bank alias only
  __shared__ float red[4][3][16][17];   // pad 17 -> conflict-free reduce
  const int tid = threadIdx.x, lane = tid & 63, wv = tid >> 6;
  const int bg = blockIdx.x >> 6, ug = blockIdx.x & 63;
  const int brow0 = bg * 16;

  // stage w_hh slice -> LDS fp16. row lr = gate*16+c -> whh[gate*1024 + ug*16 + c]
  for (int lr = 0; lr < 48; lr++) {
    const float* srow = whh + (size_t)((lr >> 4) * NH + ug * 16 + (lr & 15)) * NH;
    float4 v = *(const float4*)(srow + tid * 4);
    f16x4 t = {(f16)v.x, (f16)v.y, (f16)v.z, (f16)v.w};
    *(f16x4*)(&wl[lr][tid * 4]) = t;
  }
  const int b = tid >> 4, u = tid & 15;
  const int ugl = ug * 16 + u;
  const float bh_r = bhh[ugl], bh_z = bhh[NH + ugl], bh_n = bhh[2 * NH + ugl];
  float hown = 0.f;
  uint32_t* myc = cnt + bg * 32;        // 128B-separated counters
  __syncthreads();

  #pragma unroll 1
  for (int s = 0; s < NS; s++) {
    // prefetch gx_t (independent of h) before the barrier (plain cached loads:
    // GX is read-only during this kernel, so L2 caching is safe + desirable)
    const f16* gxp = GX + ((size_t)s * NB + brow0 + b) * G3 + ugl;
    f16 gr16 = gxp[0], gz16 = gxp[NH], gn16 = gxp[2 * NH];

    if (s > 0) {
      if (tid == 0) {
        const uint32_t target = 64u * (uint32_t)s;
        while (__hip_atomic_load(myc, __ATOMIC_RELAXED, __HIP_MEMORY_SCOPE_AGENT) < target)
          __builtin_amdgcn_s_sleep(1);
      }
      __syncthreads();
    }

    const f16* hsrc = hb + (size_t)(s & 1) * NB * NH;
    // A-frags: wave wv covers k in [wv*256, wv*256+256). Loads bypass L1/L2
    // (sc0 sc1) so they observe other XCDs' write-through stores at the IF$.
    f16x8 af[8];
    {
      const f16* hrow = hsrc + (size_t)(brow0 + (lane & 15)) * NH + wv * 256 + (lane >> 4) * 8;
      asm volatile(
        "global_load_dwordx4 %0, %[p], off sc0 sc1\n\t"
        "global_load_dwordx4 %1, %[p], off offset:64 sc0 sc1\n\t"
        "global_load_dwordx4 %2, %[p], off offset:128 sc0 sc1\n\t"
        "global_load_dwordx4 %3, %[p], off offset:192 sc0 sc1\n\t"
        "global_load_dwordx4 %4, %[p], off offset:256 sc0 sc1\n\t"
        "global_load_dwordx4 %5, %[p], off offset:320 sc0 sc1\n\t"
        "global_load_dwordx4 %6, %[p], off offset:384 sc0 sc1\n\t"
        "global_load_dwordx4 %7, %[p], off offset:448 sc0 sc1\n\t"
        "s_waitcnt vmcnt(0)"
        : "=&v"(af[0]), "=&v"(af[1]), "=&v"(af[2]), "=&v"(af[3]),
          "=&v"(af[4]), "=&v"(af[5]), "=&v"(af[6]), "=&v"(af[7])
        : [p] "v"(hrow)
        : "memory");
      __builtin_amdgcn_sched_barrier(0);  // rule #18: keep MFMA after the waitcnt
    }
    f32x4 acc[3] = {};
    #pragma unroll
    for (int kk = 0; kk < 8; kk++) {
      const int kof = wv * 256 + kk * 32 + (lane >> 4) * 8;
      #pragma unroll
      for (int n = 0; n < 3; n++) {
        f16x8 bfrag = *(const f16x8*)(&wl[n * 16 + (lane & 15)][kof]);
        acc[n] = __builtin_amdgcn_mfma_f32_16x16x32_f16(af[kk], bfrag, acc[n], 0, 0, 0);
      }
    }
    {
      const int col = lane & 15, rq = lane >> 4;
      #pragma unroll
      for (int n = 0; n < 3; n++)
        #pragma unroll
        for (int q = 0; q < 4; q++)
          red[wv][n][rq * 4 + q][col] = acc[n][q];
    }
    __syncthreads();
    float ghr = bh_r, ghz = bh_z, ghn = bh_n;
    #pragma unroll
    for (int w2 = 0; w2 < 4; w2++) {
      ghr += red[w2][0][b][u];
      ghz += red[w2][1][b][u];
      ghn += red[w2][2][b][u];
    }
    const float xr = (float)gr16, xz = (float)gz16, xn = (float)gn16;
    const float r = 1.f / (1.f + __expf(-(xr + ghr)));
    const float z = 1.f / (1.f + __expf(-(xz + ghz)));
    float nv;
    {
      const float a = xn + r * ghn;
      const float t = __expf(-2.f * fabsf(a));
      nv = (1.f - t) / (1.f + t);
      nv = a < 0.f ? -nv : nv;
    }
    hown = (1.f - z) * nv + z * hown;
    // write-through store of own h element to the coherence point
    {
      f16* hdst = hb + (size_t)((s + 1) & 1) * NB * NH + (size_t)(brow0 + b) * NH + ugl;
      union { f16 h; unsigned short u; } cv;
      cv.h = (f16)hown;
      unsigned int uval = cv.u;
      asm volatile("global_store_short %0, %1, off sc0 sc1"
                   :: "v"(hdst), "v"(uval) : "memory");
      asm volatile("s_waitcnt vmcnt(0)" ::: "memory");  // store visible at IF$
    }
    if (s == NS - 1) hlast[(size_t)(brow0 + b) * NH + ugl] = hown;
    __syncthreads();   // all threads' stores done + red[] WAR safety
    if (tid == 0)
      __hip_atomic_fetch_add(myc, 1u, __ATOMIC_RELAXED, __HIP_MEMORY_SCOPE_AGENT);
  }
}

// ---------------------------------------------------------------- FC head
__global__ __launch_bounds__(64) void fc_k(const float* __restrict__ hl,
                                           const float* __restrict__ fw,
                                           const float* __restrict__ fb,
                                           float* __restrict__ out) {
  int b = blockIdx.x, t = threadIdx.x;
  float a0 = 0.f, a1 = 0.f;
  for (int k = t; k < NH; k += 64) {
    float h = hl[b * NH + k];
    a0 += h * fw[k];
    a1 += h * fw[NH + k];
  }
  #pragma unroll
  for (int off = 32; off; off >>= 1) {
    a0 += __shfl_down(a0, off);
    a1 += __shfl_down(a1, off);
  }
  if (t == 0) {
    out[b * 2 + 0] = a0 + fb[0];
    out[b * 2 + 1] = a1 + fb[1];
  }
}

// ---------------------------------------------------------------- launcher
extern "C" void kernel_launch(void* const* d_in, const int* in_sizes, int n_in,
                              void* d_out, int out_size, void* d_ws, size_t ws_size,
                              hipStream_t stream) {
  const int*   seq = (const int*)d_in[0];
  const float* emb = (const float*)d_in[1];
  const float* wih = (const float*)d_in[2];
  const float* whh = (const float*)d_in[3];
  const float* bih = (const float*)d_in[4];
  const float* bhh = (const float*)d_in[5];
  const float* fcw = (const float*)d_in[6];
  const float* fcb = (const float*)d_in[7];
  float* out = (float*)d_out;

  char* ws = (char*)d_ws;
  size_t off = 0;
  f16* X = (f16*)(ws + off);   off += (size_t)NS * NB * NE * 2;   // 33.6 MB
  f16* W16 = (f16*)(ws + off); off += (size_t)G3 * NE * 2;        // 3.1 MB
  f16* GX = (f16*)(ws + off);  off += (size_t)NS * NB * G3 * 2;   // 201 MB
  f16* HB = (f16*)(ws + off);  off += (size_t)2 * NB * NH * 2;    // 256 KB
  float* HL = (float*)(ws + off); off += (size_t)NB * NH * 4;     // 256 KB
  uint32_t* CNT = (uint32_t*)(ws + off); off += 4 * 128;
  if (ws_size < off) return;  // insufficient workspace -> fail visibly, no OOB

  hipMemsetAsync(HB, 0, (size_t)NB * NH * 2, stream);  // h0 = 0 (parity-0 buffer)
  hipMemsetAsync(CNT, 0, 4 * 128, stream);             // barrier counters

  embed_k<<<(NS * NB) / 4, 256, 0, stream>>>(seq, emb, X);
  wconv<<<(G3 * NE) / 1024, 256, 0, stream>>>(wih, W16);
  gemm_gx<<<256 * 24, 256, 0, stream>>>(X, W16, bih, GX);
  gru_rec<<<256, 256, 0, stream>>>(whh, bhh, GX, HB, HL, CNT);
  fc_k<<<NB, 64, 0, stream>>>(HL, fcw, fcb, out);
}